// Round 12
// baseline (219.797 us; speedup 1.0000x reference)
//
#include <hip/hip_runtime.h>
#include <hip/hip_bf16.h>

#define BN    4
#define NN    2048
#define INF   128
#define HH    8
#define HD    16
#define ALPHA 0.2f
#define DECAY 0.1f

typedef __attribute__((ext_vector_type(8))) short short8;
typedef __attribute__((ext_vector_type(4))) float float4v;
typedef __attribute__((ext_vector_type(2))) float f32x2;

// v_cvt_pk_bf16_f32: 2 f32 -> packed 2x bf16 (RNE), single HW op.
// (Proven correct on this toolchain in rounds 3/6/8/10/11 PASS.)
__device__ __forceinline__ unsigned cvt_pk_bf16(float lo, float hi) {
    unsigned r;
    asm("v_cvt_pk_bf16_f32 %0, %1, %2" : "=v"(r) : "v"(lo), "v"(hi));
    return r;
}

// ---------------- Kernel 1: fused [max over tm] + [proj hf/es/ed] ----------
// blocks 0..1023: grid-stride max reduction (HBM-bound).
// blocks 1024..5119: projection, 2 nodes per block (latency-bound; overlaps).
// hf is written in MFMA-B-fragment-major layout: for lane (q,im) of a wave,
// hf[((b*8+h)*64 + J)*512 + lane*8 + k] = h[b][h][j = J*32 + q*8 + k][d = im]
// so k_attn's hv load is lane-consecutive (1KB coalesced per wave).
__launch_bounds__(256, 8)
__global__ void k_setup(const float* __restrict__ x,
                        const float* __restrict__ W,
                        const float* __restrict__ a,
                        const float* __restrict__ tm,
                        unsigned* __restrict__ ct,
                        __hip_bfloat16* __restrict__ hf,
                        float* __restrict__ es, float* __restrict__ ed) {
    if (blockIdx.x < 1024) {
        // ---- role A: ct = max(tm), values >= 0 so u32-compare == f32-compare
        const uint4* p = (const uint4*)tm;
        const int nvec = BN * NN * NN / 4;  // 4,194,304
        int idx = blockIdx.x * 256 + threadIdx.x;
        const int stride = 1024 * 256;
        unsigned m = 0u;
        for (int i = idx; i < nvec; i += stride) {
            uint4 v = p[i];
            m = max(m, v.x); m = max(m, v.y); m = max(m, v.z); m = max(m, v.w);
        }
        float fm = __uint_as_float(m);
        #pragma unroll
        for (int o = 32; o >= 1; o >>= 1) fm = fmaxf(fm, __shfl_xor(fm, o));
        __shared__ float sm[4];
        if ((threadIdx.x & 63) == 0) sm[threadIdx.x >> 6] = fm;
        __syncthreads();
        if (threadIdx.x == 0) {
            float mm = fmaxf(fmaxf(sm[0], sm[1]), fmaxf(sm[2], sm[3]));
            atomicMax(ct, __float_as_uint(mm));
        }
    } else {
        // ---- role B: h = x W ; hf (fragment-major bf16) ; es ; ed
        int bid = blockIdx.x - 1024;          // 0..4095
        int sub = threadIdx.x >> 7;           // which of 2 nodes
        int tt  = threadIdx.x & 127;
        int nn  = bid * 2 + sub;              // global node 0..8191 (= b*NN+n)
        __shared__ float xs[2][INF];
        xs[sub][tt] = x[(size_t)nn * INF + tt];
        __syncthreads();
        int h = tt >> 4, d = tt & 15;
        const float* Wp = W + (h * INF) * HD + d;
        float acc = 0.f;
        #pragma unroll 16
        for (int i = 0; i < INF; i++) acc += xs[sub][i] * Wp[i * HD];
        int b = nn >> 11, n = nn & 2047;
        // fragment-major store: J = j-block of 32, lane = q*16 + d, k = j&7
        {
            int J  = n >> 5;
            int q2 = (n >> 3) & 3;
            int k  = n & 7;
            hf[((size_t)(b * HH + h) * 64 + J) * 512 + (q2 * 16 + d) * 8 + k]
                = __float2bfloat16(acc);
        }
        float s  = acc * a[h * 2 * HD + d];
        float dd = acc * a[h * 2 * HD + HD + d];
        #pragma unroll
        for (int o = 8; o >= 1; o >>= 1) { s += __shfl_xor(s, o); dd += __shfl_xor(dd, o); }
        if (d == 0) {
            es[(b * HH + h) * NN + n] = s;
            ed[(b * HH + h) * NN + n] = dd;
        }
    }
}

// ---------------- Kernel 2: fused scores + partial softmax + PV (MFMA) -----
// grid: B * 2(j-half) * 128(i-tile) = 1024 blocks -> 4 blocks/CU, 32 waves/CU.
// block: 512 thr = 8 waves, wave = head. NEW: 256-j barrier periods (R=4, was
// 8x128) -- halves barrier convoys + staging-loop overhead. Per period the
// block stages masked tw = exp(-DECAY*(ct-t)) into a DOUBLE-BUFFERED LDS
// plane of 16x260 (two disjoint 128-col chunks per thread, same conflict-free
// map as before). __expf everywhere (r10); row-sums via ones-MFMA and the
// r+2 prefetch pinned by sched_barrier(0) (r11).
__launch_bounds__(512, 8)
__global__ void k_attn(const int* __restrict__ adj,
                       const float* __restrict__ tm,
                       const __hip_bfloat16* __restrict__ hf,
                       const float* __restrict__ es, const float* __restrict__ ed,
                       const unsigned* __restrict__ ctp,
                       float* __restrict__ pacc, float* __restrict__ pl) {
    int t    = threadIdx.x;
    int w    = t >> 6;          // head
    int lane = t & 63;
    int q    = lane >> 4;       // quad 0..3
    int im   = lane & 15;       // i within tile / d for B-frag
    int bx   = blockIdx.x;
    int b    = bx >> 8;
    int half = (bx >> 7) & 1;
    int i0   = (bx & 127) << 4;
    int i    = i0 + im;
    int jb   = half << 10;      // j-half base: 0 or 1024
    const int R = 4;            // 4 periods x 256 j = 1024 j

    __shared__ float tws[2][16][260];   // double buffer; 256 cols + 4 pad

    float ctv = __uint_as_float(*ctp);
    float c0  = -DECAY * ctv;                 // tw = exp(DECAY*t + c0)
    float es_i = es[(b * HH + w) * NN + i];
    f32x2 es2 = {es_i, es_i};
    f32x2 al2 = {ALPHA, ALPHA};

    const float* ed_p = ed + (size_t)(b * HH + w) * NN + jb + q * 8;
    // fragment-major h: base for this (b,w) + this lane's 8-element chunk
    const __hip_bfloat16* hf_p = hf + (size_t)(b * HH + w) * 32768 + lane * 8;
    int Jb = (jb >> 5);         // 0 or 32

    // staging map: 512 threads x (4+4) elements = 16 rows x (128+128) cols
    int srow = t >> 5;            // 0..15
    int scol = (t & 31) << 2;     // 0,4,...,124 (chunk A); +128 = chunk B
    const int*   adj_s = adj + ((size_t)(b * NN + i0 + srow)) * NN + jb + scol;
    const float* tm_s  = tm  + ((size_t)(b * NN + i0 + srow)) * NN + jb + scol;

    float4v acc  = {0.f, 0.f, 0.f, 0.f};
    float4v accl = {0.f, 0.f, 0.f, 0.f};   // row-sum accumulator (ones-MFMA)

    // all-ones B fragment (bf16 1.0 = 0x3F80)
    union { unsigned u[4]; short8 v; } ones;
    #pragma unroll
    for (int k = 0; k < 4; k++) ones.u[k] = 0x3F803F80u;

    auto stage4 = [&](float* dst, int4 av, float4 tv) {
        float w0 = (av.x != 0) ? __expf(fmaf(DECAY, tv.x, c0)) : 0.f;
        float w1 = (av.y != 0) ? __expf(fmaf(DECAY, tv.y, c0)) : 0.f;
        float w2 = (av.z != 0) ? __expf(fmaf(DECAY, tv.z, c0)) : 0.f;
        float w3 = (av.w != 0) ? __expf(fmaf(DECAY, tv.w, c0)) : 0.f;
        *(float4*)dst = make_float4(w0, w1, w2, w3);
    };

    // prologue: stage period 0 (cols scol and scol+128), prefetch period 1
    {
        int4   a0 = *(const int4*)(adj_s);
        float4 t0 = *(const float4*)(tm_s);
        int4   a1 = *(const int4*)(adj_s + 128);
        float4 t1 = *(const float4*)(tm_s + 128);
        stage4(&tws[0][srow][scol],       a0, t0);
        stage4(&tws[0][srow][scol + 128], a1, t1);
    }
    int4   paA = *(const int4*)(adj_s + 256);
    float4 ptA = *(const float4*)(tm_s + 256);
    int4   paB = *(const int4*)(adj_s + 384);
    float4 ptB = *(const float4*)(tm_s + 384);
    __syncthreads();

    for (int r = 0; r < R; r++) {
        int cur = r & 1;

        // issue period r+2's prefetch FIRST, then pin it with a scheduling
        // fence so it cannot be sunk to its use next period (r7 failure mode).
        int4   npaA = paA, npaB = paB;
        float4 nptA = ptA, nptB = ptB;
        if (r + 2 < R) {
            npaA = *(const int4*)(adj_s + (r + 2) * 256);
            nptA = *(const float4*)(tm_s + (r + 2) * 256);
            npaB = *(const int4*)(adj_s + (r + 2) * 256 + 128);
            nptB = *(const float4*)(tm_s + (r + 2) * 256 + 128);
        }
        __builtin_amdgcn_sched_barrier(0);

        // stage period r+1 into the other buffer (consumes paA/B, ptA/B)
        if (r + 1 < R) {
            stage4(&tws[cur ^ 1][srow][scol],       paA, ptA);
            stage4(&tws[cur ^ 1][srow][scol + 128], paB, ptB);
        }
        paA = npaA; ptA = nptA; paB = npaB; ptB = nptB;

        // consume period r: 8 c-steps of 32 j each
        #pragma unroll
        for (int c8 = 0; c8 < 8; c8++) {
            int jl = c8 * 32 + q * 8;
            int jglob = r * 256 + c8 * 32;

            float4 w01 = *(const float4*)&tws[cur][im][jl];
            float4 w23 = *(const float4*)&tws[cur][im][jl + 4];
            float4 e0 = *(const float4*)(ed_p + jglob);
            float4 e1 = *(const float4*)(ed_p + jglob + 4);
            uint4  hv = *(const uint4*)(hf_p + (size_t)(Jb + r * 8 + c8) * 512);

            union { unsigned u[4]; short8 v; } af;

            auto do_pair = [&](float elo, float ehi, float wlo, float whi) -> unsigned {
                f32x2 e  = {elo, ehi};
                f32x2 wv = {wlo, whi};
                f32x2 s0 = es2 + e;                                   // v_pk_add
                f32x2 sc = __builtin_elementwise_max(s0, s0 * al2);   // v_pk_mul+max
                f32x2 uu = sc * wv;                                   // v_pk_mul
                float p0 = __expf(uu.x);                              // v_mul+v_exp
                float p1 = __expf(uu.y);
                p0 = (wlo > 0.f) ? p0 : 0.f;                          // masked -> 0
                p1 = (whi > 0.f) ? p1 : 0.f;
                return cvt_pk_bf16(p0, p1);
            };
            af.u[0] = do_pair(e0.x, e0.y, w01.x, w01.y);
            af.u[1] = do_pair(e0.z, e0.w, w01.z, w01.w);
            af.u[2] = do_pair(e1.x, e1.y, w23.x, w23.y);
            af.u[3] = do_pair(e1.z, e1.w, w23.z, w23.w);

            union { uint4 uu4; short8 v; } bf;
            bf.uu4 = hv;
            acc  = __builtin_amdgcn_mfma_f32_16x16x32_bf16(af.v, bf.v,   acc,  0, 0, 0);
            accl = __builtin_amdgcn_mfma_f32_16x16x32_bf16(af.v, ones.v, accl, 0, 0, 0);
        }
        __syncthreads();
    }

    // dump partials: pacc[((bx*8+w)*16+row)*16+col], pl[bx*128+w*16+row]
    // D layout: col=lane&15, row=q*4+reg. accl[r] = l(q*4+r) at every col
    // (row-sum of P row q*4+r; B=ones is layout-invariant across cols).
    float* pb = pacc + (((size_t)bx * 8 + w) * 16) * 16;
    #pragma unroll
    for (int r = 0; r < 4; r++) {
        int row = q * 4 + r;
        pb[row * 16 + im] = acc[r];
        if (im == 0) pl[(size_t)bx * 128 + w * 16 + row] = accl[r];
    }
}

// ---------------- Kernel 3: combine j-halves + normalize + ELU -------------
__launch_bounds__(256, 8)
__global__ void k_fin(const float* __restrict__ pacc, const float* __restrict__ pl,
                      float* __restrict__ out) {
    int o = blockIdx.x * 256 + threadIdx.x;   // B*N*H*HD = 1,048,576
    int b   = o >> 18;
    int rem = o & 262143;
    int i   = rem >> 7;
    int hd  = rem & 127;
    int h   = hd >> 4;
    int d   = hd & 15;
    int it  = i >> 4;
    int row = i & 15;
    int blk0 = (b * 2 + 0) * 128 + it;
    int blk1 = blk0 + 128;
    float a0 = pacc[(((size_t)blk0 * 8 + h) * 16 + row) * 16 + d];
    float a1 = pacc[(((size_t)blk1 * 8 + h) * 16 + row) * 16 + d];
    float l  = pl[(size_t)blk0 * 128 + h * 16 + row]
             + pl[(size_t)blk1 * 128 + h * 16 + row];
    float v = (a0 + a1) / l;
    v = (v > 0.f) ? v : expm1f(v);   // ELU
    out[o] = v;
}

extern "C" void kernel_launch(void* const* d_in, const int* in_sizes, int n_in,
                              void* d_out, int out_size, void* d_ws, size_t ws_size,
                              hipStream_t stream) {
    const float* x   = (const float*)d_in[0];  // node_features fp32
    const int*   adj = (const int*)d_in[1];    // adjacency int32
    const float* tm  = (const float*)d_in[2];  // time_matrix fp32
    const float* W   = (const float*)d_in[3];  // W fp32
    const float* a   = (const float*)d_in[4];  // a fp32
    float* out = (float*)d_out;                // fp32 output

    float* wsf = (float*)d_ws;
    unsigned* ct = (unsigned*)wsf;                           // 1 word
    float* es = wsf + 64;                                    // 65,536
    float* ed = es + BN * HH * NN;                           // 65,536
    __hip_bfloat16* hf = (__hip_bfloat16*)(ed + BN * HH * NN);   // 1,048,576 bf16
    float* pacc = (float*)(hf + BN * HH * HD * NN);          // 2,097,152
    float* pl   = pacc + 1024 * 2048;                        // 131,072
    // total ws use ~= 11.5 MB

    hipMemsetAsync(d_ws, 0, 4, stream);                      // ct = 0.0f (t >= 0)
    k_setup<<<1024 + 4096, 256, 0, stream>>>(x, W, a, tm, ct, hf, es, ed);
    k_attn <<<BN * 2 * (NN / 16), 512, 0, stream>>>(adj, tm, hf, es, ed, ct, pacc, pl);
    k_fin  <<<(BN * NN * HH * HD) / 256, 256, 0, stream>>>(pacc, pl, out);
}